// Round 1
// 796.633 us; speedup vs baseline: 1.2368x; 1.2368x over previous
//
#include <hip/hip_runtime.h>
#include <hip/hip_bf16.h>

#define HEADS 8
#define DIM_HEAD 32
#define GROUPS 8
#define CCH 256            // channels
#define NTOK 4096          // d*h*w = 16^3
#define JSPLIT 4
#define EPS 1e-5f

// -------------------- 1. GroupNorm stats --------------------
// One block per group; group g owns contiguous rows [g*32, (g+1)*32) of (256,4096).
__global__ void gn_stats(const float* __restrict__ x, float* __restrict__ stats) {
    const int g = blockIdx.x;
    const int M = (CCH / GROUPS) * NTOK;   // 131072 contiguous floats
    const float* p = x + (size_t)g * M;
    float s = 0.f, ss = 0.f;
    for (int i = threadIdx.x; i < M; i += blockDim.x) {
        float v = p[i];
        s += v; ss += v * v;
    }
    // wave64 reduce
    #pragma unroll
    for (int off = 32; off; off >>= 1) {
        s  += __shfl_down(s,  off);
        ss += __shfl_down(ss, off);
    }
    __shared__ float sh0[8], sh1[8];
    const int wave = threadIdx.x >> 6, lane = threadIdx.x & 63;
    if (lane == 0) { sh0[wave] = s; sh1[wave] = ss; }
    __syncthreads();
    if (threadIdx.x == 0) {
        float S = 0.f, SS = 0.f;
        const int nw = blockDim.x >> 6;
        for (int w = 0; w < nw; ++w) { S += sh0[w]; SS += sh1[w]; }
        const float mean = S / (float)M;
        const float var  = SS / (float)M - mean * mean;
        stats[g * 2]     = mean;
        stats[g * 2 + 1] = rsqrtf(var + EPS);
    }
}

// -------------------- 2. Apply norm --------------------
__global__ void gn_apply(const float* __restrict__ x, const float* __restrict__ gamma,
                         const float* __restrict__ beta, const float* __restrict__ stats,
                         float* __restrict__ xn) {
    const int idx = blockIdx.x * blockDim.x + threadIdx.x;  // over CCH*NTOK
    const int c = idx >> 12;          // /4096
    const int g = c >> 5;             // /32
    const float mean = stats[g * 2];
    const float rstd = stats[g * 2 + 1];
    xn[idx] = (x[idx] - mean) * rstd * gamma[c] + beta[c];
}

// -------------------- 3. QKV GEMM (naive, K=256) --------------------
// Output layout transposed for attention: qkvt[part][h][j][d], d contiguous.
__global__ void qkv_gemm(const float* __restrict__ xn, const float* __restrict__ w,
                         const float* __restrict__ b, float* __restrict__ qkvt) {
    const int j = blockIdx.x * blockDim.x + threadIdx.x;   // 0..4095
    const int o = blockIdx.y;                              // 0..767
    const float* wr = w + (size_t)o * CCH;
    float acc = b[o];
    #pragma unroll 8
    for (int c = 0; c < CCH; ++c)
        acc = fmaf(wr[c], xn[(size_t)c * NTOK + j], acc);
    const int part = o >> 8;          // 0=q,1=k,2=v
    const int hd = o & 255;
    const int h = hd >> 5, d = hd & 31;
    qkvt[(((size_t)part * HEADS + h) * NTOK + j) * DIM_HEAD + d] = acc;
}

// -------------------- 4. Attention partial (blocked online softmax over j-chunk) --------------------
// JB-blocked: 16 independent QK dots (wave-uniform K/V addresses -> scalar loads,
// prefetchable), one branchless rescale per block, then 16 exps + 16 PV rank-1 updates.
#define JB 16
__global__ __launch_bounds__(256, 2)
void attn_partial(const float* __restrict__ qkvt,
                  float* __restrict__ pm, float* __restrict__ pl,
                  float* __restrict__ pacc) {
    const int i = blockIdx.x * blockDim.x + threadIdx.x;   // query index 0..4095
    const int h = blockIdx.y;                              // head
    const int s = blockIdx.z;                              // j chunk
    const float* qp = qkvt + ((size_t)h * NTOK + i) * DIM_HEAD;
    float q[DIM_HEAD];
    #pragma unroll
    for (int d0 = 0; d0 < DIM_HEAD; d0 += 4) {
        float4 t = *(const float4*)(qp + d0);
        q[d0] = t.x; q[d0+1] = t.y; q[d0+2] = t.z; q[d0+3] = t.w;
    }
    const float scale = 0.17677669529663687f;  // 32^-0.5
    float m = -1e30f, l = 0.f;
    float acc[DIM_HEAD];
    #pragma unroll
    for (int d = 0; d < DIM_HEAD; ++d) acc[d] = 0.f;

    const float* kbase = qkvt + (size_t)(HEADS + h)     * NTOK * DIM_HEAD;
    const float* vbase = qkvt + (size_t)(2 * HEADS + h) * NTOK * DIM_HEAD;
    const int j0 = s * (NTOK / JSPLIT);

    for (int jb = 0; jb < NTOK / JSPLIT; jb += JB) {
        // ---- 16 independent scores (ILP; K addresses wave-uniform) ----
        float sc[JB];
        #pragma unroll
        for (int u = 0; u < JB; ++u) {
            const float* kp = kbase + (size_t)(j0 + jb + u) * DIM_HEAD;
            float s0 = 0.f, s1 = 0.f, s2 = 0.f, s3 = 0.f;
            #pragma unroll
            for (int d0 = 0; d0 < DIM_HEAD; d0 += 4) {
                float4 kv = *(const float4*)(kp + d0);
                s0 = fmaf(q[d0],   kv.x, s0);
                s1 = fmaf(q[d0+1], kv.y, s1);
                s2 = fmaf(q[d0+2], kv.z, s2);
                s3 = fmaf(q[d0+3], kv.w, s3);
            }
            sc[u] = (s0 + s1 + s2 + s3) * scale;
        }
        // ---- block max + single branchless rescale ----
        float bm = sc[0];
        #pragma unroll
        for (int u = 1; u < JB; ++u) bm = fmaxf(bm, sc[u]);
        const float mn = fmaxf(m, bm);
        const float corr = __expf(m - mn);   // ==1 when max didn't move
        m = mn;
        l *= corr;
        #pragma unroll
        for (int d = 0; d < DIM_HEAD; ++d) acc[d] *= corr;
        // ---- probabilities ----
        float p[JB];
        #pragma unroll
        for (int u = 0; u < JB; ++u) { p[u] = __expf(sc[u] - m); l += p[u]; }
        // ---- PV rank-1 updates (V addresses wave-uniform) ----
        #pragma unroll
        for (int u = 0; u < JB; ++u) {
            const float* vp = vbase + (size_t)(j0 + jb + u) * DIM_HEAD;
            #pragma unroll
            for (int d0 = 0; d0 < DIM_HEAD; d0 += 4) {
                float4 vv = *(const float4*)(vp + d0);
                acc[d0]   = fmaf(p[u], vv.x, acc[d0]);
                acc[d0+1] = fmaf(p[u], vv.y, acc[d0+1]);
                acc[d0+2] = fmaf(p[u], vv.z, acc[d0+2]);
                acc[d0+3] = fmaf(p[u], vv.w, acc[d0+3]);
            }
        }
    }
    const size_t pidx = ((size_t)(h * JSPLIT + s) * NTOK + i);
    pm[pidx] = m;
    pl[pidx] = l;
    float* pa = pacc + pidx * DIM_HEAD;
    #pragma unroll
    for (int d0 = 0; d0 < DIM_HEAD; d0 += 4) {
        float4 t;
        t.x = acc[d0]; t.y = acc[d0+1]; t.z = acc[d0+2]; t.w = acc[d0+3];
        *(float4*)(pa + d0) = t;
    }
}

// -------------------- 5. Combine partial softmax states --------------------
__global__ void attn_combine(const float* __restrict__ pm, const float* __restrict__ pl,
                             const float* __restrict__ pacc, float* __restrict__ att) {
    const int i = blockIdx.x * blockDim.x + threadIdx.x;   // 0..4095
    const int h = blockIdx.y;
    float mv[JSPLIT], lv[JSPLIT];
    float mM = -1e30f;
    #pragma unroll
    for (int s = 0; s < JSPLIT; ++s) {
        const size_t pidx = ((size_t)(h * JSPLIT + s) * NTOK + i);
        mv[s] = pm[pidx];
        lv[s] = pl[pidx];
        mM = fmaxf(mM, mv[s]);
    }
    float wv[JSPLIT];
    float denom = 0.f;
    #pragma unroll
    for (int s = 0; s < JSPLIT; ++s) {
        wv[s] = __expf(mv[s] - mM);
        denom += lv[s] * wv[s];
    }
    const float inv = 1.f / denom;
    #pragma unroll
    for (int d0 = 0; d0 < DIM_HEAD; d0 += 4) {
        float o0 = 0.f, o1 = 0.f, o2 = 0.f, o3 = 0.f;
        #pragma unroll
        for (int s = 0; s < JSPLIT; ++s) {
            const size_t pidx = ((size_t)(h * JSPLIT + s) * NTOK + i);
            float4 a = *(const float4*)(pacc + pidx * DIM_HEAD + d0);
            o0 = fmaf(a.x, wv[s], o0);
            o1 = fmaf(a.y, wv[s], o1);
            o2 = fmaf(a.z, wv[s], o2);
            o3 = fmaf(a.w, wv[s], o3);
        }
        att[(size_t)(h * DIM_HEAD + d0    ) * NTOK + i] = o0 * inv;
        att[(size_t)(h * DIM_HEAD + d0 + 1) * NTOK + i] = o1 * inv;
        att[(size_t)(h * DIM_HEAD + d0 + 2) * NTOK + i] = o2 * inv;
        att[(size_t)(h * DIM_HEAD + d0 + 3) * NTOK + i] = o3 * inv;
    }
}

// -------------------- 6. Output projection + bias + residual --------------------
__global__ void out_proj(const float* __restrict__ att, const float* __restrict__ w,
                         const float* __restrict__ b, const float* __restrict__ x,
                         float* __restrict__ out) {
    const int j = blockIdx.x * blockDim.x + threadIdx.x;   // 0..4095
    const int o = blockIdx.y;                              // 0..255
    const float* wr = w + (size_t)o * CCH;
    float acc = b[o];
    #pragma unroll 8
    for (int c = 0; c < CCH; ++c)
        acc = fmaf(wr[c], att[(size_t)c * NTOK + j], acc);
    out[(size_t)o * NTOK + j] = acc + x[(size_t)o * NTOK + j];
}

extern "C" void kernel_launch(void* const* d_in, const int* in_sizes, int n_in,
                              void* d_out, int out_size, void* d_ws, size_t ws_size,
                              hipStream_t stream) {
    const float* x     = (const float*)d_in[0];
    const float* gamma = (const float*)d_in[1];
    const float* beta  = (const float*)d_in[2];
    const float* w_qkv = (const float*)d_in[3];
    const float* b_qkv = (const float*)d_in[4];
    const float* w_out = (const float*)d_in[5];
    const float* b_out = (const float*)d_in[6];
    float* out = (float*)d_out;

    float* ws    = (float*)d_ws;
    float* stats = ws;                       // 64
    float* xn    = stats + 64;               // 256*4096          = 1048576
    float* qkvt  = xn    + 1048576;          // 768*4096          = 3145728
    float* pm    = qkvt  + 3145728;          // 8*4*4096          = 131072
    float* pl    = pm    + 131072;           // 131072
    float* pacc  = pl    + 131072;           // 8*4*4096*32       = 4194304
    float* att   = pacc  + 4194304;          // 256*4096          = 1048576
    // total ~38.8 MB of f32 scratch

    gn_stats<<<GROUPS, 256, 0, stream>>>(x, stats);
    gn_apply<<<(CCH * NTOK) / 256, 256, 0, stream>>>(x, gamma, beta, stats, xn);
    {
        dim3 g(NTOK / 256, 3 * CCH);
        qkv_gemm<<<g, 256, 0, stream>>>(xn, w_qkv, b_qkv, qkvt);
    }
    {
        dim3 g(NTOK / 256, HEADS, JSPLIT);
        attn_partial<<<g, 256, 0, stream>>>(qkvt, pm, pl, pacc);
    }
    {
        dim3 g(NTOK / 256, HEADS);
        attn_combine<<<g, 256, 0, stream>>>(pm, pl, pacc, att);
    }
    {
        dim3 g(NTOK / 256, CCH);
        out_proj<<<g, 256, 0, stream>>>(att, w_out, b_out, x, out);
    }
}

// Round 2
// 693.754 us; speedup vs baseline: 1.4202x; 1.1483x over previous
//
#include <hip/hip_runtime.h>
#include <hip/hip_bf16.h>

#define HEADS 8
#define DIM_HEAD 32
#define GROUPS 8
#define CCH 256            // channels
#define NTOK 4096          // d*h*w = 16^3
#define EPS 1e-5f
#define GN_SPLIT 32
#define MAX_JSPLIT 16

// -------------------- 1a. GroupNorm partial stats --------------------
// grid (GN_SPLIT, GROUPS); each block reduces a 4096-float slice.
__global__ void gn_stats_partial(const float* __restrict__ x, float* __restrict__ part) {
    const int g  = blockIdx.y;
    const int sp = blockIdx.x;
    const int M = (CCH / GROUPS) * NTOK;        // 131072 contiguous floats per group
    const int chunk = M / GN_SPLIT;             // 4096
    const float4* p = (const float4*)(x + (size_t)g * M + (size_t)sp * chunk);
    float s = 0.f, ss = 0.f;
    for (int i = threadIdx.x; i < chunk / 4; i += blockDim.x) {   // 4 iters @256 thr
        float4 v = p[i];
        s  += v.x + v.y + v.z + v.w;
        ss += v.x*v.x + v.y*v.y + v.z*v.z + v.w*v.w;
    }
    #pragma unroll
    for (int off = 32; off; off >>= 1) {
        s  += __shfl_down(s,  off);
        ss += __shfl_down(ss, off);
    }
    __shared__ float sh0[8], sh1[8];
    const int wave = threadIdx.x >> 6, lane = threadIdx.x & 63;
    if (lane == 0) { sh0[wave] = s; sh1[wave] = ss; }
    __syncthreads();
    if (threadIdx.x == 0) {
        float S = 0.f, SS = 0.f;
        const int nw = blockDim.x >> 6;
        for (int w = 0; w < nw; ++w) { S += sh0[w]; SS += sh1[w]; }
        part[(g * GN_SPLIT + sp) * 2]     = S;
        part[(g * GN_SPLIT + sp) * 2 + 1] = SS;
    }
}

// -------------------- 1b. GroupNorm finalize --------------------
__global__ void gn_stats_final(const float* __restrict__ part, float* __restrict__ stats) {
    const int g = blockIdx.x;           // 8 blocks, 64 threads
    float s = 0.f, ss = 0.f;
    if (threadIdx.x < GN_SPLIT) {
        s  = part[(g * GN_SPLIT + threadIdx.x) * 2];
        ss = part[(g * GN_SPLIT + threadIdx.x) * 2 + 1];
    }
    #pragma unroll
    for (int off = 16; off; off >>= 1) {
        s  += __shfl_down(s,  off);
        ss += __shfl_down(ss, off);
    }
    if (threadIdx.x == 0) {
        const int M = (CCH / GROUPS) * NTOK;
        const float mean = s / (float)M;
        const float var  = ss / (float)M - mean * mean;
        stats[g * 2]     = mean;
        stats[g * 2 + 1] = rsqrtf(var + EPS);
    }
}

// -------------------- 2. Apply norm --------------------
__global__ void gn_apply(const float* __restrict__ x, const float* __restrict__ gamma,
                         const float* __restrict__ beta, const float* __restrict__ stats,
                         float* __restrict__ xn) {
    const int idx = blockIdx.x * blockDim.x + threadIdx.x;  // over CCH*NTOK
    const int c = idx >> 12;          // /4096
    const int g = c >> 5;             // /32
    const float mean = stats[g * 2];
    const float rstd = stats[g * 2 + 1];
    xn[idx] = (x[idx] - mean) * rstd * gamma[c] + beta[c];
}

// -------------------- 3. QKV GEMM (naive, K=256) --------------------
// Output layout transposed for attention: qkvt[part][h][j][d], d contiguous.
__global__ void qkv_gemm(const float* __restrict__ xn, const float* __restrict__ w,
                         const float* __restrict__ b, float* __restrict__ qkvt) {
    const int j = blockIdx.x * blockDim.x + threadIdx.x;   // 0..4095
    const int o = blockIdx.y;                              // 0..767
    const float* wr = w + (size_t)o * CCH;
    float acc = b[o];
    #pragma unroll 8
    for (int c = 0; c < CCH; ++c)
        acc = fmaf(wr[c], xn[(size_t)c * NTOK + j], acc);
    const int part = o >> 8;          // 0=q,1=k,2=v
    const int hd = o & 255;
    const int h = hd >> 5, d = hd & 31;
    qkvt[(((size_t)part * HEADS + h) * NTOK + j) * DIM_HEAD + d] = acc;
}

// -------------------- 4. Attention partial (blocked online softmax over j-chunk) --------------------
// JB-blocked: 16 independent QK dots (wave-uniform K/V addresses -> scalar loads,
// prefetchable), one branchless rescale per block, then 16 exps + 16 PV rank-1 updates.
// j-split count is runtime (gridDim.z), chosen by host from ws_size.
#define JB 16
__global__ __launch_bounds__(256, 8)
void attn_partial(const float* __restrict__ qkvt,
                  float* __restrict__ pm, float* __restrict__ pl,
                  float* __restrict__ pacc, const int jlen) {
    const int i = blockIdx.x * blockDim.x + threadIdx.x;   // query index 0..4095
    const int h = blockIdx.y;                              // head
    const int s = blockIdx.z;                              // j chunk
    const int js = gridDim.z;
    const float* qp = qkvt + ((size_t)h * NTOK + i) * DIM_HEAD;
    float q[DIM_HEAD];
    #pragma unroll
    for (int d0 = 0; d0 < DIM_HEAD; d0 += 4) {
        float4 t = *(const float4*)(qp + d0);
        q[d0] = t.x; q[d0+1] = t.y; q[d0+2] = t.z; q[d0+3] = t.w;
    }
    const float scale = 0.17677669529663687f;  // 32^-0.5
    float m = -1e30f, l = 0.f;
    float acc[DIM_HEAD];
    #pragma unroll
    for (int d = 0; d < DIM_HEAD; ++d) acc[d] = 0.f;

    const float* kbase = qkvt + (size_t)(HEADS + h)     * NTOK * DIM_HEAD;
    const float* vbase = qkvt + (size_t)(2 * HEADS + h) * NTOK * DIM_HEAD;
    const int j0 = s * jlen;

    for (int jb = 0; jb < jlen; jb += JB) {
        // ---- 16 independent scores (ILP; K addresses wave-uniform) ----
        float sc[JB];
        #pragma unroll
        for (int u = 0; u < JB; ++u) {
            const float* kp = kbase + (size_t)(j0 + jb + u) * DIM_HEAD;
            float s0 = 0.f, s1 = 0.f, s2 = 0.f, s3 = 0.f;
            #pragma unroll
            for (int d0 = 0; d0 < DIM_HEAD; d0 += 4) {
                float4 kv = *(const float4*)(kp + d0);
                s0 = fmaf(q[d0],   kv.x, s0);
                s1 = fmaf(q[d0+1], kv.y, s1);
                s2 = fmaf(q[d0+2], kv.z, s2);
                s3 = fmaf(q[d0+3], kv.w, s3);
            }
            sc[u] = (s0 + s1 + s2 + s3) * scale;
        }
        // ---- block max + single branchless rescale ----
        float bm = sc[0];
        #pragma unroll
        for (int u = 1; u < JB; ++u) bm = fmaxf(bm, sc[u]);
        const float mn = fmaxf(m, bm);
        const float corr = __expf(m - mn);   // ==1 when max didn't move
        m = mn;
        l *= corr;
        #pragma unroll
        for (int d = 0; d < DIM_HEAD; ++d) acc[d] *= corr;
        // ---- probabilities ----
        float p[JB];
        #pragma unroll
        for (int u = 0; u < JB; ++u) { p[u] = __expf(sc[u] - m); l += p[u]; }
        // ---- PV rank-1 updates (V addresses wave-uniform) ----
        #pragma unroll
        for (int u = 0; u < JB; ++u) {
            const float* vp = vbase + (size_t)(j0 + jb + u) * DIM_HEAD;
            #pragma unroll
            for (int d0 = 0; d0 < DIM_HEAD; d0 += 4) {
                float4 vv = *(const float4*)(vp + d0);
                acc[d0]   = fmaf(p[u], vv.x, acc[d0]);
                acc[d0+1] = fmaf(p[u], vv.y, acc[d0+1]);
                acc[d0+2] = fmaf(p[u], vv.z, acc[d0+2]);
                acc[d0+3] = fmaf(p[u], vv.w, acc[d0+3]);
            }
        }
    }
    const size_t pidx = ((size_t)(h * js + s) * NTOK + i);
    pm[pidx] = m;
    pl[pidx] = l;
    float* pa = pacc + pidx * DIM_HEAD;
    #pragma unroll
    for (int d0 = 0; d0 < DIM_HEAD; d0 += 4) {
        float4 t;
        t.x = acc[d0]; t.y = acc[d0+1]; t.z = acc[d0+2]; t.w = acc[d0+3];
        *(float4*)(pa + d0) = t;
    }
}

// -------------------- 5. Combine partial softmax states --------------------
__global__ void attn_combine(const float* __restrict__ pm, const float* __restrict__ pl,
                             const float* __restrict__ pacc, float* __restrict__ att,
                             const int js) {
    const int i = blockIdx.x * blockDim.x + threadIdx.x;   // 0..4095
    const int h = blockIdx.y;
    float mv[MAX_JSPLIT], lv[MAX_JSPLIT];
    float mM = -1e30f;
    for (int s = 0; s < js; ++s) {
        const size_t pidx = ((size_t)(h * js + s) * NTOK + i);
        mv[s] = pm[pidx];
        lv[s] = pl[pidx];
        mM = fmaxf(mM, mv[s]);
    }
    float wv[MAX_JSPLIT];
    float denom = 0.f;
    for (int s = 0; s < js; ++s) {
        wv[s] = __expf(mv[s] - mM);
        denom += lv[s] * wv[s];
    }
    const float inv = 1.f / denom;
    #pragma unroll
    for (int d0 = 0; d0 < DIM_HEAD; d0 += 4) {
        float o0 = 0.f, o1 = 0.f, o2 = 0.f, o3 = 0.f;
        for (int s = 0; s < js; ++s) {
            const size_t pidx = ((size_t)(h * js + s) * NTOK + i);
            float4 a = *(const float4*)(pacc + pidx * DIM_HEAD + d0);
            o0 = fmaf(a.x, wv[s], o0);
            o1 = fmaf(a.y, wv[s], o1);
            o2 = fmaf(a.z, wv[s], o2);
            o3 = fmaf(a.w, wv[s], o3);
        }
        att[(size_t)(h * DIM_HEAD + d0    ) * NTOK + i] = o0 * inv;
        att[(size_t)(h * DIM_HEAD + d0 + 1) * NTOK + i] = o1 * inv;
        att[(size_t)(h * DIM_HEAD + d0 + 2) * NTOK + i] = o2 * inv;
        att[(size_t)(h * DIM_HEAD + d0 + 3) * NTOK + i] = o3 * inv;
    }
}

// -------------------- 6. Output projection + bias + residual --------------------
__global__ void out_proj(const float* __restrict__ att, const float* __restrict__ w,
                         const float* __restrict__ b, const float* __restrict__ x,
                         float* __restrict__ out) {
    const int j = blockIdx.x * blockDim.x + threadIdx.x;   // 0..4095
    const int o = blockIdx.y;                              // 0..255
    const float* wr = w + (size_t)o * CCH;
    float acc = b[o];
    #pragma unroll 8
    for (int c = 0; c < CCH; ++c)
        acc = fmaf(wr[c], att[(size_t)c * NTOK + j], acc);
    out[(size_t)o * NTOK + j] = acc + x[(size_t)o * NTOK + j];
}

extern "C" void kernel_launch(void* const* d_in, const int* in_sizes, int n_in,
                              void* d_out, int out_size, void* d_ws, size_t ws_size,
                              hipStream_t stream) {
    const float* x     = (const float*)d_in[0];
    const float* gamma = (const float*)d_in[1];
    const float* beta  = (const float*)d_in[2];
    const float* w_qkv = (const float*)d_in[3];
    const float* b_qkv = (const float*)d_in[4];
    const float* w_out = (const float*)d_in[5];
    const float* b_out = (const float*)d_in[6];
    float* out = (float*)d_out;

    float* ws    = (float*)d_ws;
    float* stats = ws;                          // 64
    float* part  = stats + 64;                  // 8*32*2 = 512
    float* xn    = part  + 512;                 // 256*4096 = 1048576
    float* qkvt  = xn    + (size_t)CCH * NTOK;  // 768*4096 = 3145728
    float* pm    = qkvt  + (size_t)3 * CCH * NTOK;

    // choose j-split from available workspace (16 -> 8 -> 4 fallback)
    int js = 4;
    {
        const size_t base = 64 + 512 + (size_t)CCH * NTOK + (size_t)3 * CCH * NTOK;
        for (int cand = MAX_JSPLIT; cand >= 8; cand >>= 1) {
            const size_t need = base
                + (size_t)HEADS * cand * NTOK * (2 + DIM_HEAD)   // pm+pl+pacc
                + (size_t)CCH * NTOK;                            // att
            if (need * sizeof(float) <= ws_size) { js = cand; break; }
        }
    }
    const int jlen = NTOK / js;

    float* pl   = pm   + (size_t)HEADS * js * NTOK;
    float* pacc = pl   + (size_t)HEADS * js * NTOK;
    float* att  = pacc + (size_t)HEADS * js * NTOK * DIM_HEAD;

    {
        dim3 g(GN_SPLIT, GROUPS);
        gn_stats_partial<<<g, 256, 0, stream>>>(x, part);
    }
    gn_stats_final<<<GROUPS, 64, 0, stream>>>(part, stats);
    gn_apply<<<(CCH * NTOK) / 256, 256, 0, stream>>>(x, gamma, beta, stats, xn);
    {
        dim3 g(NTOK / 256, 3 * CCH);
        qkv_gemm<<<g, 256, 0, stream>>>(xn, w_qkv, b_qkv, qkvt);
    }
    {
        dim3 g(NTOK / 256, HEADS, js);
        attn_partial<<<g, 256, 0, stream>>>(qkvt, pm, pl, pacc, jlen);
    }
    {
        dim3 g(NTOK / 256, HEADS);
        attn_combine<<<g, 256, 0, stream>>>(pm, pl, pacc, att, js);
    }
    {
        dim3 g(NTOK / 256, CCH);
        out_proj<<<g, 256, 0, stream>>>(att, w_out, b_out, x, out);
    }
}

// Round 3
// 464.315 us; speedup vs baseline: 2.1219x; 1.4941x over previous
//
#include <hip/hip_runtime.h>
#include <hip/hip_bf16.h>

#define HEADS 8
#define DIM_HEAD 32
#define GROUPS 8
#define CCH 256            // channels
#define NTOK 4096          // d*h*w = 16^3
#define EPS 1e-5f
#define GN_SPLIT 32
#define MAX_JSPLIT 16

// -------------------- 1a. GroupNorm partial stats --------------------
__global__ void gn_stats_partial(const float* __restrict__ x, float* __restrict__ part) {
    const int g  = blockIdx.y;
    const int sp = blockIdx.x;
    const int M = (CCH / GROUPS) * NTOK;        // 131072 contiguous floats per group
    const int chunk = M / GN_SPLIT;             // 4096
    const float4* p = (const float4*)(x + (size_t)g * M + (size_t)sp * chunk);
    float s = 0.f, ss = 0.f;
    for (int i = threadIdx.x; i < chunk / 4; i += blockDim.x) {
        float4 v = p[i];
        s  += v.x + v.y + v.z + v.w;
        ss += v.x*v.x + v.y*v.y + v.z*v.z + v.w*v.w;
    }
    #pragma unroll
    for (int off = 32; off; off >>= 1) {
        s  += __shfl_down(s,  off);
        ss += __shfl_down(ss, off);
    }
    __shared__ float sh0[8], sh1[8];
    const int wave = threadIdx.x >> 6, lane = threadIdx.x & 63;
    if (lane == 0) { sh0[wave] = s; sh1[wave] = ss; }
    __syncthreads();
    if (threadIdx.x == 0) {
        float S = 0.f, SS = 0.f;
        const int nw = blockDim.x >> 6;
        for (int w = 0; w < nw; ++w) { S += sh0[w]; SS += sh1[w]; }
        part[(g * GN_SPLIT + sp) * 2]     = S;
        part[(g * GN_SPLIT + sp) * 2 + 1] = SS;
    }
}

// -------------------- 1b. GroupNorm finalize --------------------
__global__ void gn_stats_final(const float* __restrict__ part, float* __restrict__ stats) {
    const int g = blockIdx.x;           // 8 blocks, 64 threads
    float s = 0.f, ss = 0.f;
    if (threadIdx.x < GN_SPLIT) {
        s  = part[(g * GN_SPLIT + threadIdx.x) * 2];
        ss = part[(g * GN_SPLIT + threadIdx.x) * 2 + 1];
    }
    #pragma unroll
    for (int off = 16; off; off >>= 1) {
        s  += __shfl_down(s,  off);
        ss += __shfl_down(ss, off);
    }
    if (threadIdx.x == 0) {
        const int M = (CCH / GROUPS) * NTOK;
        const float mean = s / (float)M;
        const float var  = ss / (float)M - mean * mean;
        stats[g * 2]     = mean;
        stats[g * 2 + 1] = rsqrtf(var + EPS);
    }
}

// -------------------- 2. Apply norm --------------------
__global__ void gn_apply(const float* __restrict__ x, const float* __restrict__ gamma,
                         const float* __restrict__ beta, const float* __restrict__ stats,
                         float* __restrict__ xn) {
    const int idx = blockIdx.x * blockDim.x + threadIdx.x;  // over CCH*NTOK
    const int c = idx >> 12;          // /4096
    const int g = c >> 5;             // /32
    const float mean = stats[g * 2];
    const float rstd = stats[g * 2 + 1];
    xn[idx] = (x[idx] - mean) * rstd * gamma[c] + beta[c];
}

// -------------------- 3. QKV GEMM (naive, K=256) --------------------
__global__ void qkv_gemm(const float* __restrict__ xn, const float* __restrict__ w,
                         const float* __restrict__ b, float* __restrict__ qkvt) {
    const int j = blockIdx.x * blockDim.x + threadIdx.x;   // 0..4095
    const int o = blockIdx.y;                              // 0..767
    const float* wr = w + (size_t)o * CCH;
    float acc = b[o];
    #pragma unroll 8
    for (int c = 0; c < CCH; ++c)
        acc = fmaf(wr[c], xn[(size_t)c * NTOK + j], acc);
    const int part = o >> 8;          // 0=q,1=k,2=v
    const int hd = o & 255;
    const int h = hd >> 5, d = hd & 31;
    qkvt[(((size_t)part * HEADS + h) * NTOK + j) * DIM_HEAD + d] = acc;
}

// -------------------- 4. Attention partial (blocked online softmax over j-chunk) --------------------
// launch_bounds(256,4): 128-VGPR budget fits q[32]+acc[32]+sc/p[16]+pipelined loads
// without spilling (round 2 lesson: (256,8) forces 64-reg cap -> 1.5 GB scratch spill).
#define JB 16
__global__ __launch_bounds__(256, 4)
void attn_partial(const float* __restrict__ qkvt,
                  float* __restrict__ pm, float* __restrict__ pl,
                  float* __restrict__ pacc, const int jlen) {
    const int i = blockIdx.x * blockDim.x + threadIdx.x;   // query index 0..4095
    const int h = blockIdx.y;                              // head
    const int s = blockIdx.z;                              // j chunk
    const int js = gridDim.z;
    const float* qp = qkvt + ((size_t)h * NTOK + i) * DIM_HEAD;
    float q[DIM_HEAD];
    #pragma unroll
    for (int d0 = 0; d0 < DIM_HEAD; d0 += 4) {
        float4 t = *(const float4*)(qp + d0);
        q[d0] = t.x; q[d0+1] = t.y; q[d0+2] = t.z; q[d0+3] = t.w;
    }
    const float scale = 0.17677669529663687f;  // 32^-0.5
    float m = -1e30f, l = 0.f;
    float acc[DIM_HEAD];
    #pragma unroll
    for (int d = 0; d < DIM_HEAD; ++d) acc[d] = 0.f;

    const float* kbase = qkvt + (size_t)(HEADS + h)     * NTOK * DIM_HEAD;
    const float* vbase = qkvt + (size_t)(2 * HEADS + h) * NTOK * DIM_HEAD;
    const int j0 = s * jlen;

    for (int jb = 0; jb < jlen; jb += JB) {
        // ---- 16 independent scores (ILP; K addresses wave-uniform) ----
        float sc[JB];
        #pragma unroll
        for (int u = 0; u < JB; ++u) {
            const float* kp = kbase + (size_t)(j0 + jb + u) * DIM_HEAD;
            float s0 = 0.f, s1 = 0.f, s2 = 0.f, s3 = 0.f;
            #pragma unroll
            for (int d0 = 0; d0 < DIM_HEAD; d0 += 4) {
                float4 kv = *(const float4*)(kp + d0);
                s0 = fmaf(q[d0],   kv.x, s0);
                s1 = fmaf(q[d0+1], kv.y, s1);
                s2 = fmaf(q[d0+2], kv.z, s2);
                s3 = fmaf(q[d0+3], kv.w, s3);
            }
            sc[u] = (s0 + s1 + s2 + s3) * scale;
        }
        // ---- block max + single branchless rescale ----
        float bm = sc[0];
        #pragma unroll
        for (int u = 1; u < JB; ++u) bm = fmaxf(bm, sc[u]);
        const float mn = fmaxf(m, bm);
        const float corr = __expf(m - mn);   // ==1 when max didn't move
        m = mn;
        l *= corr;
        #pragma unroll
        for (int d = 0; d < DIM_HEAD; ++d) acc[d] *= corr;
        // ---- probabilities ----
        float p[JB];
        #pragma unroll
        for (int u = 0; u < JB; ++u) { p[u] = __expf(sc[u] - m); l += p[u]; }
        // ---- PV rank-1 updates (V addresses wave-uniform) ----
        #pragma unroll
        for (int u = 0; u < JB; ++u) {
            const float* vp = vbase + (size_t)(j0 + jb + u) * DIM_HEAD;
            #pragma unroll
            for (int d0 = 0; d0 < DIM_HEAD; d0 += 4) {
                float4 vv = *(const float4*)(vp + d0);
                acc[d0]   = fmaf(p[u], vv.x, acc[d0]);
                acc[d0+1] = fmaf(p[u], vv.y, acc[d0+1]);
                acc[d0+2] = fmaf(p[u], vv.z, acc[d0+2]);
                acc[d0+3] = fmaf(p[u], vv.w, acc[d0+3]);
            }
        }
    }
    const size_t pidx = ((size_t)(h * js + s) * NTOK + i);
    pm[pidx] = m;
    pl[pidx] = l;
    float* pa = pacc + pidx * DIM_HEAD;
    #pragma unroll
    for (int d0 = 0; d0 < DIM_HEAD; d0 += 4) {
        float4 t;
        t.x = acc[d0]; t.y = acc[d0+1]; t.z = acc[d0+2]; t.w = acc[d0+3];
        *(float4*)(pa + d0) = t;
    }
}

// -------------------- 5. Combine partial softmax states --------------------
__global__ void attn_combine(const float* __restrict__ pm, const float* __restrict__ pl,
                             const float* __restrict__ pacc, float* __restrict__ att,
                             const int js) {
    const int i = blockIdx.x * blockDim.x + threadIdx.x;   // 0..4095
    const int h = blockIdx.y;
    float mv[MAX_JSPLIT], lv[MAX_JSPLIT];
    float mM = -1e30f;
    for (int s = 0; s < js; ++s) {
        const size_t pidx = ((size_t)(h * js + s) * NTOK + i);
        mv[s] = pm[pidx];
        lv[s] = pl[pidx];
        mM = fmaxf(mM, mv[s]);
    }
    float wv[MAX_JSPLIT];
    float denom = 0.f;
    for (int s = 0; s < js; ++s) {
        wv[s] = __expf(mv[s] - mM);
        denom += lv[s] * wv[s];
    }
    const float inv = 1.f / denom;
    #pragma unroll
    for (int d0 = 0; d0 < DIM_HEAD; d0 += 4) {
        float o0 = 0.f, o1 = 0.f, o2 = 0.f, o3 = 0.f;
        for (int s = 0; s < js; ++s) {
            const size_t pidx = ((size_t)(h * js + s) * NTOK + i);
            float4 a = *(const float4*)(pacc + pidx * DIM_HEAD + d0);
            o0 = fmaf(a.x, wv[s], o0);
            o1 = fmaf(a.y, wv[s], o1);
            o2 = fmaf(a.z, wv[s], o2);
            o3 = fmaf(a.w, wv[s], o3);
        }
        att[(size_t)(h * DIM_HEAD + d0    ) * NTOK + i] = o0 * inv;
        att[(size_t)(h * DIM_HEAD + d0 + 1) * NTOK + i] = o1 * inv;
        att[(size_t)(h * DIM_HEAD + d0 + 2) * NTOK + i] = o2 * inv;
        att[(size_t)(h * DIM_HEAD + d0 + 3) * NTOK + i] = o3 * inv;
    }
}

// -------------------- 6. Output projection + bias + residual --------------------
__global__ void out_proj(const float* __restrict__ att, const float* __restrict__ w,
                         const float* __restrict__ b, const float* __restrict__ x,
                         float* __restrict__ out) {
    const int j = blockIdx.x * blockDim.x + threadIdx.x;   // 0..4095
    const int o = blockIdx.y;                              // 0..255
    const float* wr = w + (size_t)o * CCH;
    float acc = b[o];
    #pragma unroll 8
    for (int c = 0; c < CCH; ++c)
        acc = fmaf(wr[c], att[(size_t)c * NTOK + j], acc);
    out[(size_t)o * NTOK + j] = acc + x[(size_t)o * NTOK + j];
}

extern "C" void kernel_launch(void* const* d_in, const int* in_sizes, int n_in,
                              void* d_out, int out_size, void* d_ws, size_t ws_size,
                              hipStream_t stream) {
    const float* x     = (const float*)d_in[0];
    const float* gamma = (const float*)d_in[1];
    const float* beta  = (const float*)d_in[2];
    const float* w_qkv = (const float*)d_in[3];
    const float* b_qkv = (const float*)d_in[4];
    const float* w_out = (const float*)d_in[5];
    const float* b_out = (const float*)d_in[6];
    float* out = (float*)d_out;

    float* ws    = (float*)d_ws;
    float* stats = ws;                          // 64
    float* part  = stats + 64;                  // 8*32*2 = 512
    float* xn    = part  + 512;                 // 256*4096 = 1048576
    float* qkvt  = xn    + (size_t)CCH * NTOK;  // 768*4096 = 3145728
    float* pm    = qkvt  + (size_t)3 * CCH * NTOK;

    // choose j-split from available workspace.
    // js=8 gives 1024 blocks = 4096 waves = exactly 4 waves/SIMD at 128-VGPR budget.
    int js = 4;
    {
        const size_t base = 64 + 512 + (size_t)CCH * NTOK + (size_t)3 * CCH * NTOK;
        const size_t need8 = base
            + (size_t)HEADS * 8 * NTOK * (2 + DIM_HEAD)
            + (size_t)CCH * NTOK;
        if (need8 * sizeof(float) <= ws_size) js = 8;
    }
    const int jlen = NTOK / js;

    float* pl   = pm   + (size_t)HEADS * js * NTOK;
    float* pacc = pl   + (size_t)HEADS * js * NTOK;
    float* att  = pacc + (size_t)HEADS * js * NTOK * DIM_HEAD;

    {
        dim3 g(GN_SPLIT, GROUPS);
        gn_stats_partial<<<g, 256, 0, stream>>>(x, part);
    }
    gn_stats_final<<<GROUPS, 64, 0, stream>>>(part, stats);
    gn_apply<<<(CCH * NTOK) / 256, 256, 0, stream>>>(x, gamma, beta, stats, xn);
    {
        dim3 g(NTOK / 256, 3 * CCH);
        qkv_gemm<<<g, 256, 0, stream>>>(xn, w_qkv, b_qkv, qkvt);
    }
    {
        dim3 g(NTOK / 256, HEADS, js);
        attn_partial<<<g, 256, 0, stream>>>(qkvt, pm, pl, pacc, jlen);
    }
    {
        dim3 g(NTOK / 256, HEADS);
        attn_combine<<<g, 256, 0, stream>>>(pm, pl, pacc, att, js);
    }
    {
        dim3 g(NTOK / 256, CCH);
        out_proj<<<g, 256, 0, stream>>>(att, w_out, b_out, x, out);
    }
}

// Round 4
// 450.259 us; speedup vs baseline: 2.1882x; 1.0312x over previous
//
#include <hip/hip_runtime.h>
#include <hip/hip_bf16.h>

#define HEADS 8
#define DIM_HEAD 32
#define GROUPS 8
#define CCH 256            // channels
#define NTOK 4096          // d*h*w = 16^3
#define EPS 1e-5f
#define GN_SPLIT 32

// -------------------- 1a. GroupNorm partial stats --------------------
__global__ void gn_stats_partial(const float* __restrict__ x, float* __restrict__ part) {
    const int g  = blockIdx.y;
    const int sp = blockIdx.x;
    const int M = (CCH / GROUPS) * NTOK;        // 131072 contiguous floats per group
    const int chunk = M / GN_SPLIT;             // 4096
    const float4* p = (const float4*)(x + (size_t)g * M + (size_t)sp * chunk);
    float s = 0.f, ss = 0.f;
    for (int i = threadIdx.x; i < chunk / 4; i += blockDim.x) {
        float4 v = p[i];
        s  += v.x + v.y + v.z + v.w;
        ss += v.x*v.x + v.y*v.y + v.z*v.z + v.w*v.w;
    }
    #pragma unroll
    for (int off = 32; off; off >>= 1) {
        s  += __shfl_down(s,  off);
        ss += __shfl_down(ss, off);
    }
    __shared__ float sh0[8], sh1[8];
    const int wave = threadIdx.x >> 6, lane = threadIdx.x & 63;
    if (lane == 0) { sh0[wave] = s; sh1[wave] = ss; }
    __syncthreads();
    if (threadIdx.x == 0) {
        float S = 0.f, SS = 0.f;
        const int nw = blockDim.x >> 6;
        for (int w = 0; w < nw; ++w) { S += sh0[w]; SS += sh1[w]; }
        part[(g * GN_SPLIT + sp) * 2]     = S;
        part[(g * GN_SPLIT + sp) * 2 + 1] = SS;
    }
}

// -------------------- 1b. GroupNorm finalize --------------------
__global__ void gn_stats_final(const float* __restrict__ part, float* __restrict__ stats) {
    const int g = blockIdx.x;           // 8 blocks, 64 threads
    float s = 0.f, ss = 0.f;
    if (threadIdx.x < GN_SPLIT) {
        s  = part[(g * GN_SPLIT + threadIdx.x) * 2];
        ss = part[(g * GN_SPLIT + threadIdx.x) * 2 + 1];
    }
    #pragma unroll
    for (int off = 16; off; off >>= 1) {
        s  += __shfl_down(s,  off);
        ss += __shfl_down(ss, off);
    }
    if (threadIdx.x == 0) {
        const int M = (CCH / GROUPS) * NTOK;
        const float mean = s / (float)M;
        const float var  = ss / (float)M - mean * mean;
        stats[g * 2]     = mean;
        stats[g * 2 + 1] = rsqrtf(var + EPS);
    }
}

// -------------------- 2. Apply norm --------------------
__global__ void gn_apply(const float* __restrict__ x, const float* __restrict__ gamma,
                         const float* __restrict__ beta, const float* __restrict__ stats,
                         float* __restrict__ xn) {
    const int idx = blockIdx.x * blockDim.x + threadIdx.x;  // over CCH*NTOK
    const int c = idx >> 12;          // /4096
    const int g = c >> 5;             // /32
    const float mean = stats[g * 2];
    const float rstd = stats[g * 2 + 1];
    xn[idx] = (x[idx] - mean) * rstd * gamma[c] + beta[c];
}

// -------------------- 3. QKV GEMM, 16 outputs/thread --------------------
// Register-blocked: each thread owns one token j and QKV_OT=16 consecutive output
// rows. xn is loaded once per 16 rows (16x less L2 traffic than naive).
#define QKV_OT 16
__global__ __launch_bounds__(256)
void qkv_gemm(const float* __restrict__ xn, const float* __restrict__ w,
              const float* __restrict__ b, float* __restrict__ qkvt) {
    const int j  = blockIdx.x * blockDim.x + threadIdx.x;  // 0..4095
    const int ob = blockIdx.y * QKV_OT;                    // 0..767 step 16
    float acc[QKV_OT];
    #pragma unroll
    for (int u = 0; u < QKV_OT; ++u) acc[u] = b[ob + u];
    for (int c = 0; c < CCH; c += 4) {
        const float x0 = xn[(size_t)(c    ) * NTOK + j];
        const float x1 = xn[(size_t)(c + 1) * NTOK + j];
        const float x2 = xn[(size_t)(c + 2) * NTOK + j];
        const float x3 = xn[(size_t)(c + 3) * NTOK + j];
        #pragma unroll
        for (int u = 0; u < QKV_OT; ++u) {
            const float* wr = w + (size_t)(ob + u) * CCH + c;  // wave-uniform -> s_load
            acc[u] = fmaf(wr[0], x0, acc[u]);
            acc[u] = fmaf(wr[1], x1, acc[u]);
            acc[u] = fmaf(wr[2], x2, acc[u]);
            acc[u] = fmaf(wr[3], x3, acc[u]);
        }
    }
    // ob multiple of 16 => all 16 outputs share part & h; d = dbase + u.
    const int part = ob >> 8;
    const int h    = (ob & 255) >> 5;
    const int dbase = ob & 31;          // 0 or 16
    float* dst = qkvt + (((size_t)part * HEADS + h) * NTOK + j) * DIM_HEAD + dbase;
    #pragma unroll
    for (int u = 0; u < QKV_OT; u += 4) {
        float4 t;
        t.x = acc[u]; t.y = acc[u+1]; t.z = acc[u+2]; t.w = acc[u+3];
        *(float4*)(dst + u) = t;
    }
}

// -------------------- 4. Attention partial (blocked online softmax over j-chunk) --------------------
// launch_bounds(256,4): cap 128 VGPR; measured allocation 56 VGPR -> HW runs
// 8 waves/SIMD when the grid provides 8 blocks/CU (js=16).
#define JB 16
__global__ __launch_bounds__(256, 4)
void attn_partial(const float* __restrict__ qkvt,
                  float* __restrict__ pm, float* __restrict__ pl,
                  float* __restrict__ pacc, const int jlen) {
    const int i = blockIdx.x * blockDim.x + threadIdx.x;   // query index 0..4095
    const int h = blockIdx.y;                              // head
    const int s = blockIdx.z;                              // j chunk
    const int js = gridDim.z;
    const float* qp = qkvt + ((size_t)h * NTOK + i) * DIM_HEAD;
    float q[DIM_HEAD];
    #pragma unroll
    for (int d0 = 0; d0 < DIM_HEAD; d0 += 4) {
        float4 t = *(const float4*)(qp + d0);
        q[d0] = t.x; q[d0+1] = t.y; q[d0+2] = t.z; q[d0+3] = t.w;
    }
    const float scale = 0.17677669529663687f;  // 32^-0.5
    float m = -1e30f, l = 0.f;
    float acc[DIM_HEAD];
    #pragma unroll
    for (int d = 0; d < DIM_HEAD; ++d) acc[d] = 0.f;

    const float* kbase = qkvt + (size_t)(HEADS + h)     * NTOK * DIM_HEAD;
    const float* vbase = qkvt + (size_t)(2 * HEADS + h) * NTOK * DIM_HEAD;
    const int j0 = s * jlen;

    for (int jb = 0; jb < jlen; jb += JB) {
        // ---- 16 independent scores (ILP; K addresses wave-uniform) ----
        float sc[JB];
        #pragma unroll
        for (int u = 0; u < JB; ++u) {
            const float* kp = kbase + (size_t)(j0 + jb + u) * DIM_HEAD;
            float s0 = 0.f, s1 = 0.f, s2 = 0.f, s3 = 0.f;
            #pragma unroll
            for (int d0 = 0; d0 < DIM_HEAD; d0 += 4) {
                float4 kv = *(const float4*)(kp + d0);
                s0 = fmaf(q[d0],   kv.x, s0);
                s1 = fmaf(q[d0+1], kv.y, s1);
                s2 = fmaf(q[d0+2], kv.z, s2);
                s3 = fmaf(q[d0+3], kv.w, s3);
            }
            sc[u] = (s0 + s1 + s2 + s3) * scale;
        }
        // ---- block max + single branchless rescale ----
        float bm = sc[0];
        #pragma unroll
        for (int u = 1; u < JB; ++u) bm = fmaxf(bm, sc[u]);
        const float mn = fmaxf(m, bm);
        const float corr = __expf(m - mn);   // ==1 when max didn't move
        m = mn;
        l *= corr;
        #pragma unroll
        for (int d = 0; d < DIM_HEAD; ++d) acc[d] *= corr;
        // ---- probabilities ----
        float p[JB];
        #pragma unroll
        for (int u = 0; u < JB; ++u) { p[u] = __expf(sc[u] - m); l += p[u]; }
        // ---- PV rank-1 updates (V addresses wave-uniform) ----
        #pragma unroll
        for (int u = 0; u < JB; ++u) {
            const float* vp = vbase + (size_t)(j0 + jb + u) * DIM_HEAD;
            #pragma unroll
            for (int d0 = 0; d0 < DIM_HEAD; d0 += 4) {
                float4 vv = *(const float4*)(vp + d0);
                acc[d0]   = fmaf(p[u], vv.x, acc[d0]);
                acc[d0+1] = fmaf(p[u], vv.y, acc[d0+1]);
                acc[d0+2] = fmaf(p[u], vv.z, acc[d0+2]);
                acc[d0+3] = fmaf(p[u], vv.w, acc[d0+3]);
            }
        }
    }
    const size_t pidx = ((size_t)(h * js + s) * NTOK + i);
    pm[pidx] = m;
    pl[pidx] = l;
    float* pa = pacc + pidx * DIM_HEAD;
    #pragma unroll
    for (int d0 = 0; d0 < DIM_HEAD; d0 += 4) {
        float4 t;
        t.x = acc[d0]; t.y = acc[d0+1]; t.z = acc[d0+2]; t.w = acc[d0+3];
        *(float4*)(pa + d0) = t;
    }
}

// -------------------- 5. Combine partial softmax states (compile-time JS) --------------------
// Templated so all per-split arrays are statically indexed (runtime-indexed
// arrays go to scratch).
template <int JS>
__global__ void attn_combine(const float* __restrict__ pm, const float* __restrict__ pl,
                             const float* __restrict__ pacc, float* __restrict__ att) {
    const int i = blockIdx.x * blockDim.x + threadIdx.x;   // 0..4095
    const int h = blockIdx.y;
    float mv[JS], lv[JS];
    float mM = -1e30f;
    #pragma unroll
    for (int s = 0; s < JS; ++s) {
        const size_t pidx = ((size_t)(h * JS + s) * NTOK + i);
        mv[s] = pm[pidx];
        lv[s] = pl[pidx];
        mM = fmaxf(mM, mv[s]);
    }
    float wv[JS];
    float denom = 0.f;
    #pragma unroll
    for (int s = 0; s < JS; ++s) {
        wv[s] = __expf(mv[s] - mM);
        denom += lv[s] * wv[s];
    }
    const float inv = 1.f / denom;
    #pragma unroll
    for (int d0 = 0; d0 < DIM_HEAD; d0 += 4) {
        float o0 = 0.f, o1 = 0.f, o2 = 0.f, o3 = 0.f;
        #pragma unroll
        for (int s = 0; s < JS; ++s) {
            const size_t pidx = ((size_t)(h * JS + s) * NTOK + i);
            float4 a = *(const float4*)(pacc + pidx * DIM_HEAD + d0);
            o0 = fmaf(a.x, wv[s], o0);
            o1 = fmaf(a.y, wv[s], o1);
            o2 = fmaf(a.z, wv[s], o2);
            o3 = fmaf(a.w, wv[s], o3);
        }
        att[(size_t)(h * DIM_HEAD + d0    ) * NTOK + i] = o0 * inv;
        att[(size_t)(h * DIM_HEAD + d0 + 1) * NTOK + i] = o1 * inv;
        att[(size_t)(h * DIM_HEAD + d0 + 2) * NTOK + i] = o2 * inv;
        att[(size_t)(h * DIM_HEAD + d0 + 3) * NTOK + i] = o3 * inv;
    }
}

// -------------------- 6. Output projection, 8 outputs/thread --------------------
#define OUT_OT 8
__global__ __launch_bounds__(256)
void out_proj(const float* __restrict__ att, const float* __restrict__ w,
              const float* __restrict__ b, const float* __restrict__ x,
              float* __restrict__ out) {
    const int j  = blockIdx.x * blockDim.x + threadIdx.x;  // 0..4095
    const int ob = blockIdx.y * OUT_OT;                    // 0..255 step 8
    float acc[OUT_OT];
    #pragma unroll
    for (int u = 0; u < OUT_OT; ++u) acc[u] = b[ob + u];
    for (int c = 0; c < CCH; c += 4) {
        const float a0 = att[(size_t)(c    ) * NTOK + j];
        const float a1 = att[(size_t)(c + 1) * NTOK + j];
        const float a2 = att[(size_t)(c + 2) * NTOK + j];
        const float a3 = att[(size_t)(c + 3) * NTOK + j];
        #pragma unroll
        for (int u = 0; u < OUT_OT; ++u) {
            const float* wr = w + (size_t)(ob + u) * CCH + c;  // wave-uniform -> s_load
            acc[u] = fmaf(wr[0], a0, acc[u]);
            acc[u] = fmaf(wr[1], a1, acc[u]);
            acc[u] = fmaf(wr[2], a2, acc[u]);
            acc[u] = fmaf(wr[3], a3, acc[u]);
        }
    }
    #pragma unroll
    for (int u = 0; u < OUT_OT; ++u) {
        const size_t idx = (size_t)(ob + u) * NTOK + j;
        out[idx] = acc[u] + x[idx];
    }
}

extern "C" void kernel_launch(void* const* d_in, const int* in_sizes, int n_in,
                              void* d_out, int out_size, void* d_ws, size_t ws_size,
                              hipStream_t stream) {
    const float* x     = (const float*)d_in[0];
    const float* gamma = (const float*)d_in[1];
    const float* beta  = (const float*)d_in[2];
    const float* w_qkv = (const float*)d_in[3];
    const float* b_qkv = (const float*)d_in[4];
    const float* w_out = (const float*)d_in[5];
    const float* b_out = (const float*)d_in[6];
    float* out = (float*)d_out;

    float* ws    = (float*)d_ws;
    float* stats = ws;                          // 64
    float* part  = stats + 64;                  // 8*32*2 = 512
    float* xn    = part  + 512;                 // 256*4096 = 1048576
    float* qkvt  = xn    + (size_t)CCH * NTOK;  // 768*4096 = 3145728
    float* pm    = qkvt  + (size_t)3 * CCH * NTOK;

    // j-split: 16 (2048 blocks = 8 waves/SIMD) if workspace allows, else 8, else 4.
    // Round-2 run proved ws_size >= 92 MB (js=16 was selected there), so 16 expected.
    int js = 4;
    {
        const size_t base = 64 + 512 + (size_t)CCH * NTOK + (size_t)3 * CCH * NTOK;
        for (int cand = 16; cand >= 8; cand >>= 1) {
            const size_t need = base
                + (size_t)HEADS * cand * NTOK * (2 + DIM_HEAD)
                + (size_t)CCH * NTOK;
            if (need * sizeof(float) <= ws_size) { js = cand; break; }
        }
    }
    const int jlen = NTOK / js;

    float* pl   = pm   + (size_t)HEADS * js * NTOK;
    float* pacc = pl   + (size_t)HEADS * js * NTOK;
    float* att  = pacc + (size_t)HEADS * js * NTOK * DIM_HEAD;

    {
        dim3 g(GN_SPLIT, GROUPS);
        gn_stats_partial<<<g, 256, 0, stream>>>(x, part);
    }
    gn_stats_final<<<GROUPS, 64, 0, stream>>>(part, stats);
    gn_apply<<<(CCH * NTOK) / 256, 256, 0, stream>>>(x, gamma, beta, stats, xn);
    {
        dim3 g(NTOK / 256, 3 * CCH / QKV_OT);
        qkv_gemm<<<g, 256, 0, stream>>>(xn, w_qkv, b_qkv, qkvt);
    }
    {
        dim3 g(NTOK / 256, HEADS, js);
        attn_partial<<<g, 256, 0, stream>>>(qkvt, pm, pl, pacc, jlen);
    }
    {
        dim3 g(NTOK / 256, HEADS);
        if (js == 16)      attn_combine<16><<<g, 256, 0, stream>>>(pm, pl, pacc, att);
        else if (js == 8)  attn_combine<8><<<g, 256, 0, stream>>>(pm, pl, pacc, att);
        else               attn_combine<4><<<g, 256, 0, stream>>>(pm, pl, pacc, att);
    }
    {
        dim3 g(NTOK / 256, CCH / OUT_OT);
        out_proj<<<g, 256, 0, stream>>>(att, w_out, b_out, x, out);
    }
}